// Round 1
// baseline (181.174 us; speedup 1.0000x reference)
//
#include <hip/hip_runtime.h>
#include <stdint.h>

// MultiBoxLoss B=16, P=43008, G=128.
// R14: tail parallelization. Pass-0 histogram (bits[31:21], 1024 bins) fused
//      into k_mm's iou role (LDS hist + global atomic flush). k_fix merged
//      into k_selfix (also does partial reduction + bin-0 select; patches the
//      histogram with exact sub/add deltas). k_compact (B*42 blocks) extracts
//      the threshold-bin elements into a compact buffer (aliases bto) and
//      accumulates the above-bin sum. k_sel2 runs radix passes A/B + final
//      sum over the compacted elements only (in-LDS).
//      6 dispatches: memset(80KB), k_mm, k_selfix, k_compact, k_sel2, k_fin.

#define GC 8    // GTs per bp-role block
#define PPI 4   // priors/thread in iou role

__device__ __forceinline__ float sl1(float x) {
  float a = fabsf(x);
  return a < 1.f ? 0.5f * a * a : a - 0.5f;
}

__device__ __forceinline__ double dwave(double v) {
#pragma unroll
  for (int o = 32; o; o >>= 1) v += __shfl_down(v, o);
  return v;
}

__global__ __launch_bounds__(256) void k_mm(
    const float* __restrict__ priors, const float* __restrict__ targets,
    const float* __restrict__ loc, const float* __restrict__ conf,
    const float* __restrict__ lm, float* __restrict__ bto,
    int* __restrict__ bti, unsigned long long* __restrict__ bp,
    float* __restrict__ mine, unsigned* __restrict__ ghist,
    double* __restrict__ pll, double* __restrict__ pllm,
    double* __restrict__ plc, double* __restrict__ msum,
    int* __restrict__ pnp, int P, int G, int NIOU, int PTI, int NGC, int PC) {
  int tid = threadIdx.x;
  __shared__ char smem[16384];  // bp: sred(16KB); iou: st(7.5KB)+rs+ri+hist
  __shared__ float4 sgt[128];
  __shared__ float sga[128];

  if ((int)blockIdx.x < NIOU) {
    // ---- iou role: best-truth per prior + full per-prior loss work ----
    float* st = (float*)smem;                  // 128*15 floats
    double* rs = (double*)(smem + 7680);       // 16 doubles
    int* ri = (int*)(smem + 7808);             // 4 ints
    unsigned* hist = (unsigned*)(smem + 8192); // 1024 u32 (pass-0 hist)
    int b = blockIdx.x / PTI, tile = blockIdx.x % PTI;
    int base = tile * (256 * PPI);
    for (int i = tid; i < G * 15; i += 256)
      st[i] = targets[(size_t)b * G * 15 + i];
    for (int g = tid; g < G; g += 256) {
      const float* t = targets + ((size_t)b * G + g) * 15;
      float x1 = t[0], y1 = t[1], x2 = t[2], y2 = t[3];
      sgt[g] = make_float4(x1, y1, x2, y2);
      sga[g] = (x2 - x1) * (y2 - y1);
    }
    for (int i = tid; i < 1024; i += 256) hist[i] = 0;
    __syncthreads();

    float px1[PPI], py1[PPI], px2[PPI], py2[PPI], pa[PPI];
    float bi[PPI], sb[PPI];
    int bidx[PPI];
#pragma unroll
    for (int k = 0; k < PPI; ++k) {
      int p = base + tid + k * 256;
      int pl = p < P ? p : P - 1;
      float4 pr = ((const float4*)priors)[pl];
      px1[k] = pr.x - pr.z * 0.5f; py1[k] = pr.y - pr.w * 0.5f;
      px2[k] = pr.x + pr.z * 0.5f; py2[k] = pr.y + pr.w * 0.5f;
      pa[k] = pr.z * pr.w;
      bi[k] = 0.f; sb[k] = 1.f; bidx[k] = 0;
    }

#define IOU_BODY(T, A, GG)                                                 \
  {                                                                        \
    float iw = fminf(T.z, px2[k]) - fmaxf(T.x, px1[k]);                    \
    float ih = fminf(T.w, py2[k]) - fmaxf(T.y, py1[k]);                    \
    float inter = fmaxf(iw, 0.f) * ih;                                     \
    float S = A + pa[k];                                                   \
    if (inter * sb[k] > bi[k] * S) { bi[k] = inter; sb[k] = S; bidx[k] = GG; } \
  }
    for (int g = 0; g < G; g += 4) {
      float4 T0 = sgt[g], T1 = sgt[g + 1], T2 = sgt[g + 2], T3 = sgt[g + 3];
      float A0 = sga[g], A1 = sga[g + 1], A2 = sga[g + 2], A3 = sga[g + 3];
#pragma unroll
      for (int k = 0; k < PPI; ++k) {
        IOU_BODY(T0, A0, g)
        IOU_BODY(T1, A1, g + 1)
        IOU_BODY(T2, A2, g + 2)
        IOU_BODY(T3, A3, g + 3)
      }
    }
#undef IOU_BODY

    // ---- main phase (pre-scatter ov/ti; k_selfix corrects forced entries) --
    double ll = 0, llm = 0, lc = 0, ms = 0;
    int np = 0;
#pragma unroll
    for (int k = 0; k < PPI; ++k) {
      int p = base + tid + k * 256;
      if (p < P) {
        size_t idx = (size_t)b * P + p;
        float ov = bi[k] / (sb[k] - bi[k]);
        int ti = bidx[k];
        bto[idx] = ov;
        bti[idx] = ti;
        bool pos = ov >= 0.35f;
        float2 c = ((const float2*)conf)[idx];
        float mx = fmaxf(c.x, c.y);
        float dd = fabsf(c.x - c.y);
        float lse = mx + logf(1.f + expf(-dd));
        float ce = lse - (pos ? c.y : c.x);
        float mv = pos ? 0.f : ce;
        mine[idx] = mv;
        atomicAdd(&hist[__float_as_uint(mv) >> 21], 1u);
        ms += (double)mv;
        if (pos) {
          np++;
          lc += (double)ce;
          float4 pr = ((const float4*)priors)[p];
          const float* t = st + ti * 15;
          float rz = 1.f / pr.z, rw = 1.f / pr.w;
          float rdx = 10.f * rz, rdy = 10.f * rw;
          float gx = ((t[0] + t[2]) * 0.5f - pr.x) * rdx;
          float gy = ((t[1] + t[3]) * 0.5f - pr.y) * rdy;
          float gw = logf((t[2] - t[0]) * rz) * 5.0f;
          float gh = logf((t[3] - t[1]) * rw) * 5.0f;
          float4 ld = ((const float4*)loc)[idx];
          ll += (double)(sl1(ld.x - gx) + sl1(ld.y - gy) + sl1(ld.z - gw) +
                         sl1(ld.w - gh));
          const float2* lmd = (const float2*)lm + idx * 5;
          float s = 0.f;
#pragma unroll
          for (int j = 0; j < 5; ++j) {
            float2 lv = lmd[j];
            float ex = (t[4 + 2 * j] - pr.x) * rdx;
            float ey = (t[5 + 2 * j] - pr.y) * rdy;
            s += sl1(lv.x - ex) + sl1(lv.y - ey);
          }
          llm += (double)s;
        }
      }
    }

    ll = dwave(ll); llm = dwave(llm); lc = dwave(lc); ms = dwave(ms);
#pragma unroll
    for (int o = 32; o; o >>= 1) np += __shfl_down(np, o);
    int lane = tid & 63, wid = tid >> 6;
    if (lane == 0) {
      rs[wid] = ll; rs[4 + wid] = llm; rs[8 + wid] = lc; rs[12 + wid] = ms;
      ri[wid] = np;
    }
    __syncthreads();
    if (tid == 0) {
      pll[blockIdx.x] = rs[0] + rs[1] + rs[2] + rs[3];
      pllm[blockIdx.x] = rs[4] + rs[5] + rs[6] + rs[7];
      plc[blockIdx.x] = rs[8] + rs[9] + rs[10] + rs[11];
      msum[blockIdx.x] = rs[12] + rs[13] + rs[14] + rs[15];
      pnp[blockIdx.x] = ri[0] + ri[1] + ri[2] + ri[3];
    }
    // flush LDS hist to global (all threads past the barrier above)
    for (int i = tid; i < 1024; i += 256) {
      unsigned c = hist[i];
      if (c) atomicAdd(&ghist[b * 1024 + i], c);
    }
  } else {
    // ---- bp role: per-GT best-prior over a P-chunk ----
    unsigned long long* sred = (unsigned long long*)smem;  // GC*256
    int bc = blockIdx.x - NIOU;
    int pc = bc % PC;
    int gcb = (bc / PC) % NGC;
    int b = bc / (PC * NGC);
    int g0 = gcb * GC;

    if (tid < GC) {
      int g = g0 + tid;
      float4 v = make_float4(0.f, 0.f, 0.f, 0.f);
      if (g < G) {
        const float* t = targets + ((size_t)b * G + g) * 15;
        v = make_float4(t[0], t[1], t[2], t[3]);
      }
      sgt[tid] = v;
    }
    __syncthreads();

    float gx1[GC], gy1[GC], gx2[GC], gy2[GC], ga[GC];
#pragma unroll
    for (int j = 0; j < GC; ++j) {
      float4 T = sgt[j];
      gx1[j] = T.x; gy1[j] = T.y; gx2[j] = T.z; gy2[j] = T.w;
      ga[j] = (T.z - T.x) * (T.w - T.y);
    }

    int chunk = (P + PC - 1) / PC;
    int ps = pc * chunk;
    int pe = ps + chunk; if (pe > P) pe = P;
    int count = pe - ps;

    float bi[GC], sb[GC];
    unsigned bpp[GC];
#pragma unroll
    for (int j = 0; j < GC; ++j) { bi[j] = 0.f; sb[j] = 1.f; bpp[j] = (unsigned)(ps + tid); }

#define BP_BODY(X1, Y1, X2, Y2, AR, PP)                                     \
  {                                                                         \
    float iw = fminf(gx2[j], X2) - fmaxf(gx1[j], X1);                       \
    float ih = fminf(gy2[j], Y2) - fmaxf(gy1[j], Y1);                       \
    float inter = fmaxf(iw, 0.f) * ih;                                      \
    float S = ga[j] + AR;                                                   \
    if (inter * sb[j] > bi[j] * S) { bi[j] = inter; sb[j] = S; bpp[j] = (unsigned)PP; } \
  }
    for (int i = tid; i < count; i += 1024) {
      int p0 = ps + i;
      int i1 = i + 256, i2 = i + 512, i3 = i + 768;
      int p1 = (i1 < count) ? ps + i1 : p0;
      int p2 = (i2 < count) ? ps + i2 : p0;
      int p3 = (i3 < count) ? ps + i3 : p0;
      float4 q0 = ((const float4*)priors)[p0];
      float4 q1 = ((const float4*)priors)[p1];
      float4 q2 = ((const float4*)priors)[p2];
      float4 q3 = ((const float4*)priors)[p3];
      float ax1 = q0.x - q0.z * 0.5f, ay1 = q0.y - q0.w * 0.5f;
      float ax2 = q0.x + q0.z * 0.5f, ay2 = q0.y + q0.w * 0.5f;
      float aa = q0.z * q0.w;
      float bx1 = q1.x - q1.z * 0.5f, by1 = q1.y - q1.w * 0.5f;
      float bx2 = q1.x + q1.z * 0.5f, by2 = q1.y + q1.w * 0.5f;
      float ba = q1.z * q1.w;
      float cx1 = q2.x - q2.z * 0.5f, cy1 = q2.y - q2.w * 0.5f;
      float cx2 = q2.x + q2.z * 0.5f, cy2 = q2.y + q2.w * 0.5f;
      float ca = q2.z * q2.w;
      float dx1 = q3.x - q3.z * 0.5f, dy1 = q3.y - q3.w * 0.5f;
      float dx2 = q3.x + q3.z * 0.5f, dy2 = q3.y + q3.w * 0.5f;
      float da = q3.z * q3.w;
#pragma unroll
      for (int j = 0; j < GC; ++j) {
        BP_BODY(ax1, ay1, ax2, ay2, aa, p0)
        BP_BODY(bx1, by1, bx2, by2, ba, p1)
        BP_BODY(cx1, cy1, cx2, cy2, ca, p2)
        BP_BODY(dx1, dy1, dx2, dy2, da, p3)
      }
    }
#undef BP_BODY

#pragma unroll
    for (int j = 0; j < GC; ++j) {
      float iou = bi[j] / (sb[j] - bi[j]);
      unsigned long long pk =
          ((unsigned long long)__float_as_uint(iou) << 32) | (unsigned)(~bpp[j]);
      sred[j * 256 + tid] = pk;
    }
    __syncthreads();
    {
      int j = tid >> 5, s = tid & 31;
      unsigned long long m = sred[j * 256 + s];
#pragma unroll
      for (int t = 1; t < 8; ++t) {
        unsigned long long v = sred[j * 256 + s + t * 32];
        if (v > m) m = v;
      }
      __syncthreads();
      sred[j * 256 + s] = m;
    }
    __syncthreads();
    if (tid < GC) {
      unsigned long long m = sred[tid * 256];
      for (int s = 1; s < 32; ++s) {
        unsigned long long v = sred[tid * 256 + s];
        if (v > m) m = v;
      }
      int g = g0 + tid;
      if (g < G) atomicMax(&bp[(size_t)b * G + g], m);
    }
  }
}

// per-b merged kernel: forced-entry fixup (exact deltas, identical float
// paths; patches mine + ghist), partial reduction, fast paths, and the
// pass-0 bin select from ghist. Writes selstate {t,k1} (t=-1 => pfs done).
__global__ __launch_bounds__(1024) void k_selfix(
    const unsigned long long* __restrict__ bp, const float* __restrict__ bto,
    const int* __restrict__ bti, const float* __restrict__ conf,
    const float* __restrict__ loc, const float* __restrict__ lm,
    const float* __restrict__ priors, const float* __restrict__ targets,
    float* __restrict__ mine, unsigned* __restrict__ ghist,
    const int* __restrict__ pnp, const double* __restrict__ msum,
    const double* __restrict__ pll, const double* __restrict__ pllm,
    const double* __restrict__ plc, int* __restrict__ num_pos,
    double* __restrict__ pllb, double* __restrict__ pllmb,
    double* __restrict__ plcb, int* __restrict__ selstate,
    double* __restrict__ pfs_b, int P, int G, int PTI) {
  int b = blockIdx.x, tid = threadIdx.x;
  __shared__ unsigned spp[128];
  __shared__ double rs[16 * 5];
  __shared__ int ris[16];
  __shared__ unsigned S[1024];
  __shared__ double sdel[4];
  __shared__ int sdnp, sav, smode;
  __shared__ long long sk;

  // ---- part 1: forced-entry fixup (threads 0..G-1) ----
  double dll = 0, dllm = 0, dlc = 0, dms = 0;
  int dnp = 0;
  unsigned pp = 0;
  bool valid = false;
  if (tid < G) {
    unsigned long long m = bp[(size_t)b * G + tid];
    pp = ~(unsigned)m;
    float val = __uint_as_float((unsigned)(m >> 32));
    spp[tid] = pp;
    valid = val >= 0.2f;
  }
  int av = __syncthreads_or((tid < G && valid) ? 1 : 0);
  bool win = false;
  if (tid < G) {
    win = true;
    for (int g2 = tid + 1; g2 < G; ++g2)
      if (spp[g2] == pp) { win = false; break; }
  }
  if (win) {
    size_t idx = (size_t)b * P + pp;
    float ov_o = bto[idx];
    int ti_o = bti[idx];
    float ov_n = valid ? 2.0f : ov_o;
    int ti_n = tid;
    bool pos_o = ov_o >= 0.35f, pos_n = ov_n >= 0.35f;

    float2 c = ((const float2*)conf)[idx];
    float mx = fmaxf(c.x, c.y);
    float dd = fabsf(c.x - c.y);
    float lse = mx + logf(1.f + expf(-dd));
    float ce_o = lse - (pos_o ? c.y : c.x);
    float ce_n = lse - (pos_n ? c.y : c.x);
    float mv_o = mine[idx];
    float mv_n = pos_n ? 0.f : ce_n;
    if (mv_n != mv_o) {
      mine[idx] = mv_n;
      atomicSub(&ghist[b * 1024 + (__float_as_uint(mv_o) >> 21)], 1u);
      atomicAdd(&ghist[b * 1024 + (__float_as_uint(mv_n) >> 21)], 1u);
    }
    dms = (double)mv_n - (double)mv_o;
    dnp = (pos_n ? 1 : 0) - (pos_o ? 1 : 0);
    dlc = (pos_n ? (double)ce_n : 0.0) - (pos_o ? (double)ce_o : 0.0);

    if (pos_o || pos_n) {
      float4 pr = ((const float4*)priors)[pp];
      float rz = 1.f / pr.z, rw = 1.f / pr.w;
      float rdx = 10.f * rz, rdy = 10.f * rw;
      float4 ld = ((const float4*)loc)[idx];
      const float2* lmd = (const float2*)lm + idx * 5;
      float2 lv[5];
#pragma unroll
      for (int j = 0; j < 5; ++j) lv[j] = lmd[j];
      for (int pass = 0; pass < 2; ++pass) {
        bool act = pass ? pos_n : pos_o;
        int ti = pass ? ti_n : ti_o;
        if (!act) continue;
        const float* t = targets + ((size_t)b * G + ti) * 15;
        float gx = ((t[0] + t[2]) * 0.5f - pr.x) * rdx;
        float gy = ((t[1] + t[3]) * 0.5f - pr.y) * rdy;
        float gw = logf((t[2] - t[0]) * rz) * 5.0f;
        float gh = logf((t[3] - t[1]) * rw) * 5.0f;
        double l = (double)(sl1(ld.x - gx) + sl1(ld.y - gy) +
                            sl1(ld.z - gw) + sl1(ld.w - gh));
        float s = 0.f;
#pragma unroll
        for (int j = 0; j < 5; ++j) {
          float ex = (t[4 + 2 * j] - pr.x) * rdx;
          float ey = (t[5 + 2 * j] - pr.y) * rdy;
          s += sl1(lv[j].x - ex) + sl1(lv[j].y - ey);
        }
        if (pass) { dll += l; dllm += (double)s; }
        else { dll -= l; dllm -= (double)s; }
      }
    }
  }
  dll = dwave(dll); dllm = dwave(dllm); dlc = dwave(dlc); dms = dwave(dms);
#pragma unroll
  for (int o = 32; o; o >>= 1) dnp += __shfl_down(dnp, o);
  int lane = tid & 63, wid = tid >> 6;
  if (lane == 0) {
    rs[wid] = dll; rs[16 + wid] = dllm; rs[32 + wid] = dlc; rs[48 + wid] = dms;
    ris[wid] = dnp;
  }
  __syncthreads();
  if (tid == 0) {
    double a = 0, c2 = 0, d2 = 0, m2 = 0;
    int n2 = 0;
    for (int i = 0; i < 16; ++i) {
      a += rs[i]; c2 += rs[16 + i]; d2 += rs[32 + i]; m2 += rs[48 + i];
      n2 += ris[i];
    }
    sdel[0] = a; sdel[1] = c2; sdel[2] = d2; sdel[3] = m2;
    sdnp = n2; sav = av;
  }
  __syncthreads();

  // ---- part 2: reduce iou-role partials ----
  double a = 0, cc = 0, d = 0, ms = 0;
  int n = 0;
  for (int i = tid; i < PTI; i += 1024) {
    int ix = b * PTI + i;
    a += pll[ix]; cc += pllm[ix]; d += plc[ix]; ms += msum[ix]; n += pnp[ix];
  }
  a = dwave(a); cc = dwave(cc); d = dwave(d); ms = dwave(ms);
#pragma unroll
  for (int o = 32; o; o >>= 1) n += __shfl_down(n, o);
  if (lane == 0) {
    rs[wid] = a; rs[16 + wid] = cc; rs[32 + wid] = d; rs[48 + wid] = ms;
    ris[wid] = n;
  }
  __syncthreads();
  if (tid == 0) {
    double A = 0, C = 0, D = 0, MS = 0;
    int npos = 0;
    for (int i = 0; i < 16; ++i) {
      A += rs[i]; C += rs[16 + i]; D += rs[32 + i]; MS += rs[48 + i];
      npos += ris[i];
    }
    A += sdel[0]; C += sdel[1]; D += sdel[2]; MS += sdel[3];
    npos += sdnp;
    if (!sav) { A = 0; C = 0; D = 0; npos = 0; }
    num_pos[b] = npos;
    pllb[b] = A; pllmb[b] = C; plcb[b] = D;
    long long k = 7LL * (long long)npos;
    long long cap = P - 1;
    int md = 1;
    if (k <= 0) { pfs_b[b] = 0.0; selstate[2 * b] = -1; md = 0; }
    else if (k >= cap) { pfs_b[b] = MS; selstate[2 * b] = -1; md = 0; }
    smode = md; sk = k;
  }
  __syncthreads();
  if (!smode) return;
  long long k = sk;

  // ---- part 3: pass-0 select from ghist (suffix-scan over 1024 bins) ----
  S[tid] = ghist[b * 1024 + tid];
  __syncthreads();
  for (int off = 1; off < 1024; off <<= 1) {
    unsigned add = (tid + off < 1024) ? S[tid + off] : 0;
    __syncthreads();
    S[tid] += add;
    __syncthreads();
  }
  int cnt_ = __syncthreads_count((long long)S[tid] >= k);
  int seg = cnt_ - 1;
  if (tid == seg) {
    long long cum = (seg + 1 < 1024) ? (long long)S[seg + 1] : 0;
    selstate[2 * b] = seg;
    selstate[2 * b + 1] = (int)(k - cum);
  }
}

// parallel sweep: above-bin sum (per-block partials, deterministic per-block)
// + compaction of the threshold-bin elements into cbuf (aliases bto).
__global__ __launch_bounds__(256) void k_compact(
    const int* __restrict__ selstate, const float* __restrict__ mine,
    float* __restrict__ cbuf, unsigned* __restrict__ cntb,
    double* __restrict__ part_hi, int P, int NCC) {
  int b = blockIdx.x / NCC, blk = blockIdx.x % NCC;
  int t = selstate[2 * b];
  if (t < 0) return;
  __shared__ unsigned lcnt, lbase;
  __shared__ double sa[4];
  if (threadIdx.x == 0) lcnt = 0;
  __syncthreads();
  int base = blk * 1024;
  double acc = 0;
  float keep[4];
  int nk = 0;
  for (int i = threadIdx.x; i < 1024; i += 256) {
    int p = base + i;
    if (p < P) {
      unsigned bb = __float_as_uint(mine[(size_t)b * P + p]);
      int bin = (int)(bb >> 21);
      if (bin > t) acc += (double)__uint_as_float(bb);
      else if (bin == t) keep[nk++] = __uint_as_float(bb);
    }
  }
  unsigned myoff = nk ? atomicAdd(&lcnt, (unsigned)nk) : 0u;
  __syncthreads();
  if (threadIdx.x == 0) lbase = lcnt ? atomicAdd(&cntb[b], lcnt) : 0u;
  __syncthreads();
  unsigned wb = lbase + myoff;
  for (int j = 0; j < nk; ++j) cbuf[(size_t)b * P + wb + j] = keep[j];
  acc = dwave(acc);
  int lane = threadIdx.x & 63, wid = threadIdx.x >> 6;
  if (lane == 0) sa[wid] = acc;
  __syncthreads();
  if (threadIdx.x == 0)
    part_hi[(size_t)b * NCC + blk] = sa[0] + sa[1] + sa[2] + sa[3];
}

// per-b: radix passes A/B + final sum over the compacted bin-t elements.
__global__ __launch_bounds__(1024) void k_sel2(
    const int* __restrict__ selstate, const float* __restrict__ cbuf,
    const unsigned* __restrict__ cntb, const double* __restrict__ part_hi,
    double* __restrict__ pfs_b, int P, int NCC) {
  int b = blockIdx.x, tid = threadIdx.x;
  int t = selstate[2 * b];
  if (t < 0) return;
  long long k1 = (long long)selstate[2 * b + 1];
  int n = (int)cntb[b];
  const float* row = cbuf + (size_t)b * P;
  __shared__ unsigned hs[2048];
  __shared__ unsigned S[1024];
  __shared__ double rs[16];
  __shared__ int spf21, sk2;
  __shared__ unsigned stb;
  __shared__ double stie;

  // pass A: bits[20:10] within bin t (2048 bins)
  hs[tid] = 0; hs[tid + 1024] = 0;
  __syncthreads();
  for (int i = tid; i < n; i += 1024) {
    unsigned bb = __float_as_uint(row[i]);
    atomicAdd(&hs[(bb >> 10) & 2047], 1u);
  }
  __syncthreads();
  {
    unsigned h0 = hs[tid * 2], h1v = hs[tid * 2 + 1];
    S[tid] = h0 + h1v;
    __syncthreads();
    for (int off = 1; off < 1024; off <<= 1) {
      unsigned add = (tid + off < 1024) ? S[tid + off] : 0;
      __syncthreads();
      S[tid] += add;
      __syncthreads();
    }
    int cnt_ = __syncthreads_count((long long)S[tid] >= k1);
    int seg = cnt_ - 1;
    if (tid == seg) {
      long long cum = (seg + 1 < 1024) ? (long long)S[seg + 1] : 0;
      int bin = seg * 2;
      if (cum + h1v >= k1) bin = seg * 2 + 1;
      else cum += h1v;
      spf21 = (t << 11) | bin;
      sk2 = (int)(k1 - cum);
    }
  }
  __syncthreads();
  int pf21 = spf21;

  // pass B: bits[9:0] (1024 bins)
  hs[tid] = 0;
  __syncthreads();
  for (int i = tid; i < n; i += 1024) {
    unsigned bb = __float_as_uint(row[i]);
    if ((int)(bb >> 10) == pf21) atomicAdd(&hs[bb & 1023], 1u);
  }
  __syncthreads();
  {
    S[tid] = hs[tid];
    __syncthreads();
    for (int off = 1; off < 1024; off <<= 1) {
      unsigned add = (tid + off < 1024) ? S[tid + off] : 0;
      __syncthreads();
      S[tid] += add;
      __syncthreads();
    }
    long long kk = (long long)sk2;
    int cnt_ = __syncthreads_count((long long)S[tid] >= kk);
    int seg = cnt_ - 1;
    if (tid == seg) {
      long long cum = (seg + 1 < 1024) ? (long long)S[seg + 1] : 0;
      unsigned tb = ((unsigned)pf21 << 10) | (unsigned)seg;
      stb = tb;
      stie = (double)(kk - cum) * (double)__uint_as_float(tb);
    }
  }
  __syncthreads();

  unsigned tb = stb;
  double v = 0.0;
  for (int i = tid; i < n; i += 1024) {
    unsigned bb = __float_as_uint(row[i]);
    if (bb > tb) v += (double)__uint_as_float(bb);
  }
  v = dwave(v);
  int lane = tid & 63, wid = tid >> 6;
  if (lane == 0) rs[wid] = v;
  __syncthreads();
  if (tid == 0) {
    double hi = 0;
    for (int j = 0; j < NCC; ++j) hi += part_hi[(size_t)b * NCC + j];
    double tot = 0;
    for (int i = 0; i < 16; ++i) tot += rs[i];
    pfs_b[b] = hi + tot + stie;
  }
}

__global__ void k_fin(const double* __restrict__ pllb,
                      const double* __restrict__ pllmb,
                      const double* __restrict__ plcb,
                      const double* __restrict__ pfs_b,
                      const int* __restrict__ num_pos, float* __restrict__ out,
                      int B) {
  if (threadIdx.x == 0) {
    double A = 0, C = 0, D = 0, F = 0, N = 0;
    for (int i = 0; i < B; ++i) {
      A += pllb[i]; C += pllmb[i]; D += plcb[i]; F += pfs_b[i];
      N += (double)num_pos[i];
    }
    if (N < 1.0) N = 1.0;
    out[0] = (float)(A / N);
    out[1] = (float)((D + F) / N);
    out[2] = (float)(C / N);
  }
}

extern "C" void kernel_launch(void* const* d_in, const int* in_sizes, int n_in,
                              void* d_out, int out_size, void* d_ws,
                              size_t ws_size, hipStream_t stream) {
  const float* loc = (const float*)d_in[0];
  const float* conf = (const float*)d_in[1];
  const float* lm = (const float*)d_in[2];
  const float* priors = (const float*)d_in[3];
  const float* targets = (const float*)d_in[4];

  int P = in_sizes[3] / 4;
  int B = in_sizes[0] / (4 * P);
  int G = in_sizes[4] / (15 * B);
  int PTI = (P + 256 * PPI - 1) / (256 * PPI);
  int NIOU = B * PTI;
  int NGC = (G + GC - 1) / GC;
  int PC = 8;
  int NBP = B * NGC * PC;
  int NCC = (P + 1023) / 1024;

  char* w = (char*)d_ws;
  size_t off = 0;
  // ---- zeroed region: bp + ghist + cnt ----
  unsigned long long* bp = (unsigned long long*)(w + off);
  off += (size_t)B * G * 8;
  unsigned* ghist = (unsigned*)(w + off);
  off += (size_t)B * 1024 * 4;
  unsigned* cntb = (unsigned*)(w + off);
  off += (size_t)B * 4;
  size_t clear_bytes = off;
  // ---- non-zeroed (written unconditionally every call) ----
  off = (off + 255) & ~(size_t)255;
  float* bto = (float*)(w + off);  // also reused as cbuf by k_compact/k_sel2
  off += (size_t)B * P * 4;
  int* bti = (int*)(w + off);
  off += (size_t)B * P * 4;
  float* mine = (float*)(w + off);
  off += (size_t)B * P * 4;
  double* pll = (double*)(w + off);
  off += (size_t)NIOU * 8;
  double* pllm = (double*)(w + off);
  off += (size_t)NIOU * 8;
  double* plc = (double*)(w + off);
  off += (size_t)NIOU * 8;
  double* msum = (double*)(w + off);
  off += (size_t)NIOU * 8;
  int* pnp = (int*)(w + off);
  off += (size_t)NIOU * 4;
  off = (off + 7) & ~(size_t)7;
  double* part_hi = (double*)(w + off);
  off += (size_t)B * NCC * 8;
  double* pllb = (double*)(w + off);
  off += (size_t)B * 8;
  double* pllmb = (double*)(w + off);
  off += (size_t)B * 8;
  double* plcb = (double*)(w + off);
  off += (size_t)B * 8;
  double* pfs_b = (double*)(w + off);
  off += (size_t)B * 8;
  int* selstate = (int*)(w + off);
  off += (size_t)B * 2 * 4;
  int* num_pos = (int*)(w + off);
  off += (size_t)B * 4;

  hipMemsetAsync(d_ws, 0, clear_bytes, stream);

  k_mm<<<NIOU + NBP, 256, 0, stream>>>(priors, targets, loc, conf, lm, bto,
                                       bti, bp, mine, ghist, pll, pllm, plc,
                                       msum, pnp, P, G, NIOU, PTI, NGC, PC);
  k_selfix<<<B, 1024, 0, stream>>>(bp, bto, bti, conf, loc, lm, priors,
                                   targets, mine, ghist, pnp, msum, pll, pllm,
                                   plc, num_pos, pllb, pllmb, plcb, selstate,
                                   pfs_b, P, G, PTI);
  k_compact<<<B * NCC, 256, 0, stream>>>(selstate, mine, bto, cntb, part_hi,
                                         P, NCC);
  k_sel2<<<B, 1024, 0, stream>>>(selstate, bto, cntb, part_hi, pfs_b, P, NCC);
  k_fin<<<1, 64, 0, stream>>>(pllb, pllmb, plcb, pfs_b, num_pos,
                              (float*)d_out, B);
}

// Round 2
// 179.236 us; speedup vs baseline: 1.0108x; 1.0108x over previous
//
#include <hip/hip_runtime.h>
#include <stdint.h>

// MultiBoxLoss B=16, P=43008, G=128.
// R15: dispatch collapse + fast scans. 3 dispatches: memset(82KB), k_mm
//      (unchanged from R14: iou+bp roles, fused pass-0 hist), k_tail2
//      (merged selfix+compact+sel2+fin). k_tail2: B blocks x 1024 thr;
//      fixup (exact deltas), partial reduce, pass-0 select from ghist,
//      one sweep (above-bin sum + compact bin-t elems to global cbuf
//      aliasing bto), radix passes A/B over compacted elems, final sum.
//      All 1024-bin suffix scans via shfl wave-scan (3 barriers each,
//      was ~30). Final B-reduction folded in via device-scope fp64
//      atomicAdd accumulators + done-counter; last block writes out.

#define GC 8    // GTs per bp-role block
#define PPI 4   // priors/thread in iou role

__device__ __forceinline__ float sl1(float x) {
  float a = fabsf(x);
  return a < 1.f ? 0.5f * a * a : a - 0.5f;
}

__device__ __forceinline__ double dwave(double v) {
#pragma unroll
  for (int o = 32; o; o >>= 1) v += __shfl_down(v, o);
  return v;
}

// block-wide inclusive suffix scan over 1024 u32 (one per thread).
// Returns S[tid] = sum_{j>=tid} x[j]; also stores S[] to LDS for neighbor
// lookups. 3 barriers. wt must be >=16 u32 LDS.
__device__ __forceinline__ unsigned bsufscan(unsigned x, unsigned* S,
                                             unsigned* wt, int tid) {
  int lane = tid & 63, wid = tid >> 6;
  unsigned v = x;
#pragma unroll
  for (int o = 1; o < 64; o <<= 1) {
    unsigned u = __shfl_down(v, o);
    if (lane + o < 64) v += u;
  }
  if (lane == 0) wt[wid] = v;  // wave totals
  __syncthreads();
  if (wid == 0) {
    unsigned tv = (lane < 16) ? wt[lane] : 0;
#pragma unroll
    for (int o = 1; o < 16; o <<= 1) {
      unsigned u = __shfl_down(tv, o);
      if (lane + o < 64) tv += u;
    }
    if (lane < 16) wt[lane] = tv;  // suffix totals over waves
  }
  __syncthreads();
  unsigned Sv = v + ((wid < 15) ? wt[wid + 1] : 0u);
  S[tid] = Sv;
  __syncthreads();
  return Sv;
}

__global__ __launch_bounds__(256) void k_mm(
    const float* __restrict__ priors, const float* __restrict__ targets,
    const float* __restrict__ loc, const float* __restrict__ conf,
    const float* __restrict__ lm, float* __restrict__ bto,
    int* __restrict__ bti, unsigned long long* __restrict__ bp,
    float* __restrict__ mine, unsigned* __restrict__ ghist,
    double* __restrict__ pll, double* __restrict__ pllm,
    double* __restrict__ plc, double* __restrict__ msum,
    int* __restrict__ pnp, int P, int G, int NIOU, int PTI, int NGC, int PC) {
  int tid = threadIdx.x;
  __shared__ char smem[16384];  // bp: sred(16KB); iou: st(7.5KB)+rs+ri+hist
  __shared__ float4 sgt[128];
  __shared__ float sga[128];

  if ((int)blockIdx.x < NIOU) {
    // ---- iou role: best-truth per prior + full per-prior loss work ----
    float* st = (float*)smem;                  // 128*15 floats
    double* rs = (double*)(smem + 7680);       // 16 doubles
    int* ri = (int*)(smem + 7808);             // 4 ints
    unsigned* hist = (unsigned*)(smem + 8192); // 1024 u32 (pass-0 hist)
    int b = blockIdx.x / PTI, tile = blockIdx.x % PTI;
    int base = tile * (256 * PPI);
    for (int i = tid; i < G * 15; i += 256)
      st[i] = targets[(size_t)b * G * 15 + i];
    for (int g = tid; g < G; g += 256) {
      const float* t = targets + ((size_t)b * G + g) * 15;
      float x1 = t[0], y1 = t[1], x2 = t[2], y2 = t[3];
      sgt[g] = make_float4(x1, y1, x2, y2);
      sga[g] = (x2 - x1) * (y2 - y1);
    }
    for (int i = tid; i < 1024; i += 256) hist[i] = 0;
    __syncthreads();

    float px1[PPI], py1[PPI], px2[PPI], py2[PPI], pa[PPI];
    float bi[PPI], sb[PPI];
    int bidx[PPI];
#pragma unroll
    for (int k = 0; k < PPI; ++k) {
      int p = base + tid + k * 256;
      int pl = p < P ? p : P - 1;
      float4 pr = ((const float4*)priors)[pl];
      px1[k] = pr.x - pr.z * 0.5f; py1[k] = pr.y - pr.w * 0.5f;
      px2[k] = pr.x + pr.z * 0.5f; py2[k] = pr.y + pr.w * 0.5f;
      pa[k] = pr.z * pr.w;
      bi[k] = 0.f; sb[k] = 1.f; bidx[k] = 0;
    }

#define IOU_BODY(T, A, GG)                                                 \
  {                                                                        \
    float iw = fminf(T.z, px2[k]) - fmaxf(T.x, px1[k]);                    \
    float ih = fminf(T.w, py2[k]) - fmaxf(T.y, py1[k]);                    \
    float inter = fmaxf(iw, 0.f) * ih;                                     \
    float S = A + pa[k];                                                   \
    if (inter * sb[k] > bi[k] * S) { bi[k] = inter; sb[k] = S; bidx[k] = GG; } \
  }
    for (int g = 0; g < G; g += 4) {
      float4 T0 = sgt[g], T1 = sgt[g + 1], T2 = sgt[g + 2], T3 = sgt[g + 3];
      float A0 = sga[g], A1 = sga[g + 1], A2 = sga[g + 2], A3 = sga[g + 3];
#pragma unroll
      for (int k = 0; k < PPI; ++k) {
        IOU_BODY(T0, A0, g)
        IOU_BODY(T1, A1, g + 1)
        IOU_BODY(T2, A2, g + 2)
        IOU_BODY(T3, A3, g + 3)
      }
    }
#undef IOU_BODY

    // ---- main phase (pre-scatter ov/ti; k_tail2 corrects forced entries) --
    double ll = 0, llm = 0, lc = 0, ms = 0;
    int np = 0;
#pragma unroll
    for (int k = 0; k < PPI; ++k) {
      int p = base + tid + k * 256;
      if (p < P) {
        size_t idx = (size_t)b * P + p;
        float ov = bi[k] / (sb[k] - bi[k]);
        int ti = bidx[k];
        bto[idx] = ov;
        bti[idx] = ti;
        bool pos = ov >= 0.35f;
        float2 c = ((const float2*)conf)[idx];
        float mx = fmaxf(c.x, c.y);
        float dd = fabsf(c.x - c.y);
        float lse = mx + logf(1.f + expf(-dd));
        float ce = lse - (pos ? c.y : c.x);
        float mv = pos ? 0.f : ce;
        mine[idx] = mv;
        atomicAdd(&hist[__float_as_uint(mv) >> 21], 1u);
        ms += (double)mv;
        if (pos) {
          np++;
          lc += (double)ce;
          float4 pr = ((const float4*)priors)[p];
          const float* t = st + ti * 15;
          float rz = 1.f / pr.z, rw = 1.f / pr.w;
          float rdx = 10.f * rz, rdy = 10.f * rw;
          float gx = ((t[0] + t[2]) * 0.5f - pr.x) * rdx;
          float gy = ((t[1] + t[3]) * 0.5f - pr.y) * rdy;
          float gw = logf((t[2] - t[0]) * rz) * 5.0f;
          float gh = logf((t[3] - t[1]) * rw) * 5.0f;
          float4 ld = ((const float4*)loc)[idx];
          ll += (double)(sl1(ld.x - gx) + sl1(ld.y - gy) + sl1(ld.z - gw) +
                         sl1(ld.w - gh));
          const float2* lmd = (const float2*)lm + idx * 5;
          float s = 0.f;
#pragma unroll
          for (int j = 0; j < 5; ++j) {
            float2 lv = lmd[j];
            float ex = (t[4 + 2 * j] - pr.x) * rdx;
            float ey = (t[5 + 2 * j] - pr.y) * rdy;
            s += sl1(lv.x - ex) + sl1(lv.y - ey);
          }
          llm += (double)s;
        }
      }
    }

    ll = dwave(ll); llm = dwave(llm); lc = dwave(lc); ms = dwave(ms);
#pragma unroll
    for (int o = 32; o; o >>= 1) np += __shfl_down(np, o);
    int lane = tid & 63, wid = tid >> 6;
    if (lane == 0) {
      rs[wid] = ll; rs[4 + wid] = llm; rs[8 + wid] = lc; rs[12 + wid] = ms;
      ri[wid] = np;
    }
    __syncthreads();
    if (tid == 0) {
      pll[blockIdx.x] = rs[0] + rs[1] + rs[2] + rs[3];
      pllm[blockIdx.x] = rs[4] + rs[5] + rs[6] + rs[7];
      plc[blockIdx.x] = rs[8] + rs[9] + rs[10] + rs[11];
      msum[blockIdx.x] = rs[12] + rs[13] + rs[14] + rs[15];
      pnp[blockIdx.x] = ri[0] + ri[1] + ri[2] + ri[3];
    }
    // flush LDS hist to global (all threads past the barrier above)
    for (int i = tid; i < 1024; i += 256) {
      unsigned c = hist[i];
      if (c) atomicAdd(&ghist[b * 1024 + i], c);
    }
  } else {
    // ---- bp role: per-GT best-prior over a P-chunk ----
    unsigned long long* sred = (unsigned long long*)smem;  // GC*256
    int bc = blockIdx.x - NIOU;
    int pc = bc % PC;
    int gcb = (bc / PC) % NGC;
    int b = bc / (PC * NGC);
    int g0 = gcb * GC;

    if (tid < GC) {
      int g = g0 + tid;
      float4 v = make_float4(0.f, 0.f, 0.f, 0.f);
      if (g < G) {
        const float* t = targets + ((size_t)b * G + g) * 15;
        v = make_float4(t[0], t[1], t[2], t[3]);
      }
      sgt[tid] = v;
    }
    __syncthreads();

    float gx1[GC], gy1[GC], gx2[GC], gy2[GC], ga[GC];
#pragma unroll
    for (int j = 0; j < GC; ++j) {
      float4 T = sgt[j];
      gx1[j] = T.x; gy1[j] = T.y; gx2[j] = T.z; gy2[j] = T.w;
      ga[j] = (T.z - T.x) * (T.w - T.y);
    }

    int chunk = (P + PC - 1) / PC;
    int ps = pc * chunk;
    int pe = ps + chunk; if (pe > P) pe = P;
    int count = pe - ps;

    float bi[GC], sb[GC];
    unsigned bpp[GC];
#pragma unroll
    for (int j = 0; j < GC; ++j) { bi[j] = 0.f; sb[j] = 1.f; bpp[j] = (unsigned)(ps + tid); }

#define BP_BODY(X1, Y1, X2, Y2, AR, PP)                                     \
  {                                                                         \
    float iw = fminf(gx2[j], X2) - fmaxf(gx1[j], X1);                       \
    float ih = fminf(gy2[j], Y2) - fmaxf(gy1[j], Y1);                       \
    float inter = fmaxf(iw, 0.f) * ih;                                      \
    float S = ga[j] + AR;                                                   \
    if (inter * sb[j] > bi[j] * S) { bi[j] = inter; sb[j] = S; bpp[j] = (unsigned)PP; } \
  }
    for (int i = tid; i < count; i += 1024) {
      int p0 = ps + i;
      int i1 = i + 256, i2 = i + 512, i3 = i + 768;
      int p1 = (i1 < count) ? ps + i1 : p0;
      int p2 = (i2 < count) ? ps + i2 : p0;
      int p3 = (i3 < count) ? ps + i3 : p0;
      float4 q0 = ((const float4*)priors)[p0];
      float4 q1 = ((const float4*)priors)[p1];
      float4 q2 = ((const float4*)priors)[p2];
      float4 q3 = ((const float4*)priors)[p3];
      float ax1 = q0.x - q0.z * 0.5f, ay1 = q0.y - q0.w * 0.5f;
      float ax2 = q0.x + q0.z * 0.5f, ay2 = q0.y + q0.w * 0.5f;
      float aa = q0.z * q0.w;
      float bx1 = q1.x - q1.z * 0.5f, by1 = q1.y - q1.w * 0.5f;
      float bx2 = q1.x + q1.z * 0.5f, by2 = q1.y + q1.w * 0.5f;
      float ba = q1.z * q1.w;
      float cx1 = q2.x - q2.z * 0.5f, cy1 = q2.y - q2.w * 0.5f;
      float cx2 = q2.x + q2.z * 0.5f, cy2 = q2.y + q2.w * 0.5f;
      float ca = q2.z * q2.w;
      float dx1 = q3.x - q3.z * 0.5f, dy1 = q3.y - q3.w * 0.5f;
      float dx2 = q3.x + q3.z * 0.5f, dy2 = q3.y + q3.w * 0.5f;
      float da = q3.z * q3.w;
#pragma unroll
      for (int j = 0; j < GC; ++j) {
        BP_BODY(ax1, ay1, ax2, ay2, aa, p0)
        BP_BODY(bx1, by1, bx2, by2, ba, p1)
        BP_BODY(cx1, cy1, cx2, cy2, ca, p2)
        BP_BODY(dx1, dy1, dx2, dy2, da, p3)
      }
    }
#undef BP_BODY

#pragma unroll
    for (int j = 0; j < GC; ++j) {
      float iou = bi[j] / (sb[j] - bi[j]);
      unsigned long long pk =
          ((unsigned long long)__float_as_uint(iou) << 32) | (unsigned)(~bpp[j]);
      sred[j * 256 + tid] = pk;
    }
    __syncthreads();
    {
      int j = tid >> 5, s = tid & 31;
      unsigned long long m = sred[j * 256 + s];
#pragma unroll
      for (int t = 1; t < 8; ++t) {
        unsigned long long v = sred[j * 256 + s + t * 32];
        if (v > m) m = v;
      }
      __syncthreads();
      sred[j * 256 + s] = m;
    }
    __syncthreads();
    if (tid < GC) {
      unsigned long long m = sred[tid * 256];
      for (int s = 1; s < 32; ++s) {
        unsigned long long v = sred[tid * 256 + s];
        if (v > m) m = v;
      }
      int g = g0 + tid;
      if (g < G) atomicMax(&bp[(size_t)b * G + g], m);
    }
  }
}

// merged tail: fixup + reduce + select + compact + radix + final fold.
// One block per b. cbuf aliases bto (fixup reads happen before writes,
// ordered by block barriers).
__global__ __launch_bounds__(1024) void k_tail2(
    const unsigned long long* __restrict__ bp, float* __restrict__ bto,
    const int* __restrict__ bti, const float* __restrict__ conf,
    const float* __restrict__ loc, const float* __restrict__ lm,
    const float* __restrict__ priors, const float* __restrict__ targets,
    float* __restrict__ mine, unsigned* __restrict__ ghist,
    const int* __restrict__ pnp, const double* __restrict__ msum,
    const double* __restrict__ pll, const double* __restrict__ pllm,
    const double* __restrict__ plc, double* __restrict__ gacc,
    int* __restrict__ gnp, unsigned* __restrict__ done,
    float* __restrict__ out, int P, int G, int PTI, int B) {
  int b = blockIdx.x, tid = threadIdx.x;
  int lane = tid & 63, wid = tid >> 6;
  __shared__ unsigned spp[128];
  __shared__ double rs[16 * 5];
  __shared__ int ris[16];
  __shared__ unsigned S[1024];
  __shared__ unsigned hs[2048];
  __shared__ unsigned wt[16];
  __shared__ double sdel[4];
  __shared__ int sdnp, sav, smode;
  __shared__ long long sk;
  __shared__ double sA, sC, sD;
  __shared__ int snpos;
  __shared__ int st_, sk1_;
  __shared__ unsigned lcnt;
  __shared__ int spf21, sk2;
  __shared__ unsigned stb;
  __shared__ double stie;

  // ---- part 1: forced-entry fixup (threads 0..G-1) ----
  double dll = 0, dllm = 0, dlc = 0, dms = 0;
  int dnp = 0;
  unsigned pp = 0;
  bool valid = false;
  if (tid < G) {
    unsigned long long m = bp[(size_t)b * G + tid];
    pp = ~(unsigned)m;
    float val = __uint_as_float((unsigned)(m >> 32));
    spp[tid] = pp;
    valid = val >= 0.2f;
  }
  int av = __syncthreads_or((tid < G && valid) ? 1 : 0);
  bool win = false;
  if (tid < G) {
    win = true;
    for (int g2 = tid + 1; g2 < G; ++g2)
      if (spp[g2] == pp) { win = false; break; }
  }
  if (win) {
    size_t idx = (size_t)b * P + pp;
    float ov_o = bto[idx];
    int ti_o = bti[idx];
    float ov_n = valid ? 2.0f : ov_o;
    int ti_n = tid;
    bool pos_o = ov_o >= 0.35f, pos_n = ov_n >= 0.35f;

    float2 c = ((const float2*)conf)[idx];
    float mx = fmaxf(c.x, c.y);
    float dd = fabsf(c.x - c.y);
    float lse = mx + logf(1.f + expf(-dd));
    float ce_o = lse - (pos_o ? c.y : c.x);
    float ce_n = lse - (pos_n ? c.y : c.x);
    float mv_o = mine[idx];
    float mv_n = pos_n ? 0.f : ce_n;
    if (mv_n != mv_o) {
      mine[idx] = mv_n;
      atomicSub(&ghist[b * 1024 + (__float_as_uint(mv_o) >> 21)], 1u);
      atomicAdd(&ghist[b * 1024 + (__float_as_uint(mv_n) >> 21)], 1u);
    }
    dms = (double)mv_n - (double)mv_o;
    dnp = (pos_n ? 1 : 0) - (pos_o ? 1 : 0);
    dlc = (pos_n ? (double)ce_n : 0.0) - (pos_o ? (double)ce_o : 0.0);

    if (pos_o || pos_n) {
      float4 pr = ((const float4*)priors)[pp];
      float rz = 1.f / pr.z, rw = 1.f / pr.w;
      float rdx = 10.f * rz, rdy = 10.f * rw;
      float4 ld = ((const float4*)loc)[idx];
      const float2* lmd = (const float2*)lm + idx * 5;
      float2 lv[5];
#pragma unroll
      for (int j = 0; j < 5; ++j) lv[j] = lmd[j];
      for (int pass = 0; pass < 2; ++pass) {
        bool act = pass ? pos_n : pos_o;
        int ti = pass ? ti_n : ti_o;
        if (!act) continue;
        const float* t = targets + ((size_t)b * G + ti) * 15;
        float gx = ((t[0] + t[2]) * 0.5f - pr.x) * rdx;
        float gy = ((t[1] + t[3]) * 0.5f - pr.y) * rdy;
        float gw = logf((t[2] - t[0]) * rz) * 5.0f;
        float gh = logf((t[3] - t[1]) * rw) * 5.0f;
        double l = (double)(sl1(ld.x - gx) + sl1(ld.y - gy) +
                            sl1(ld.z - gw) + sl1(ld.w - gh));
        float s = 0.f;
#pragma unroll
        for (int j = 0; j < 5; ++j) {
          float ex = (t[4 + 2 * j] - pr.x) * rdx;
          float ey = (t[5 + 2 * j] - pr.y) * rdy;
          s += sl1(lv[j].x - ex) + sl1(lv[j].y - ey);
        }
        if (pass) { dll += l; dllm += (double)s; }
        else { dll -= l; dllm -= (double)s; }
      }
    }
  }
  dll = dwave(dll); dllm = dwave(dllm); dlc = dwave(dlc); dms = dwave(dms);
#pragma unroll
  for (int o = 32; o; o >>= 1) dnp += __shfl_down(dnp, o);
  if (lane == 0) {
    rs[wid] = dll; rs[16 + wid] = dllm; rs[32 + wid] = dlc; rs[48 + wid] = dms;
    ris[wid] = dnp;
  }
  __syncthreads();
  if (tid == 0) {
    double a = 0, c2 = 0, d2 = 0, m2 = 0;
    int n2 = 0;
    for (int i = 0; i < 16; ++i) {
      a += rs[i]; c2 += rs[16 + i]; d2 += rs[32 + i]; m2 += rs[48 + i];
      n2 += ris[i];
    }
    sdel[0] = a; sdel[1] = c2; sdel[2] = d2; sdel[3] = m2;
    sdnp = n2; sav = av;
  }
  __syncthreads();

  // ---- part 2: reduce iou-role partials ----
  double a = 0, cc = 0, d = 0, ms = 0;
  int n = 0;
  for (int i = tid; i < PTI; i += 1024) {
    int ix = b * PTI + i;
    a += pll[ix]; cc += pllm[ix]; d += plc[ix]; ms += msum[ix]; n += pnp[ix];
  }
  a = dwave(a); cc = dwave(cc); d = dwave(d); ms = dwave(ms);
#pragma unroll
  for (int o = 32; o; o >>= 1) n += __shfl_down(n, o);
  if (lane == 0) {
    rs[wid] = a; rs[16 + wid] = cc; rs[32 + wid] = d; rs[48 + wid] = ms;
    ris[wid] = n;
  }
  __syncthreads();
  double Fv = 0.0;  // meaningful on tid 0 only
  if (tid == 0) {
    double A = 0, C = 0, D = 0, MS = 0;
    int npos = 0;
    for (int i = 0; i < 16; ++i) {
      A += rs[i]; C += rs[16 + i]; D += rs[32 + i]; MS += rs[48 + i];
      npos += ris[i];
    }
    A += sdel[0]; C += sdel[1]; D += sdel[2]; MS += sdel[3];
    npos += sdnp;
    if (!sav) { A = 0; C = 0; D = 0; npos = 0; }
    sA = A; sC = C; sD = D; snpos = npos;
    long long k = 7LL * (long long)npos;
    long long cap = P - 1;
    int md = 1;
    if (k <= 0) { Fv = 0.0; md = 0; }
    else if (k >= cap) { Fv = MS; md = 0; }
    smode = md; sk = k;
  }
  __syncthreads();

  if (smode) {
    long long k = sk;
    // ---- part 3: pass-0 select from ghist (shfl suffix-scan, 1024 bins) --
    {
      unsigned x = ghist[b * 1024 + tid];
      unsigned Sv = bsufscan(x, S, wt, tid);
      int cnt_ = __syncthreads_count((long long)Sv >= k);
      int seg = cnt_ - 1;
      if (tid == seg) {
        long long cum = (seg + 1 < 1024) ? (long long)S[seg + 1] : 0;
        st_ = seg;
        sk1_ = (int)(k - cum);
      }
      if (tid == 0) lcnt = 0;
    }
    __syncthreads();
    int t = st_;
    long long k1 = (long long)sk1_;

    // ---- part 4: sweep mine: above-bin sum + compact bin-t to cbuf ----
    const float* mrow = mine + (size_t)b * P;
    float* crow = bto + (size_t)b * P;  // cbuf (bto no longer live)
    double acc = 0;
    for (int base0 = 0; base0 < P; base0 += 4096) {
#pragma unroll
      for (int j = 0; j < 4; ++j) {
        int p = base0 + tid + j * 1024;
        if (p < P) {
          unsigned bb = __float_as_uint(mrow[p]);
          int bin = (int)(bb >> 21);
          if (bin > t) acc += (double)__uint_as_float(bb);
          else if (bin == t) {
            unsigned pos = atomicAdd(&lcnt, 1u);
            crow[pos] = __uint_as_float(bb);
          }
        }
      }
    }
    acc = dwave(acc);
    if (lane == 0) rs[wid] = acc;
    __syncthreads();
    int nn = (int)lcnt;

    // ---- part 5a: pass A hist (bits[20:10], 2048 bins) over cbuf ----
    hs[tid] = 0; hs[tid + 1024] = 0;
    __syncthreads();
    for (int i = tid; i < nn; i += 1024) {
      unsigned bb = __float_as_uint(crow[i]);
      atomicAdd(&hs[(bb >> 10) & 2047], 1u);
    }
    __syncthreads();
    {
      unsigned h0 = hs[tid * 2], h1v = hs[tid * 2 + 1];
      unsigned Sv = bsufscan(h0 + h1v, S, wt, tid);
      int cnt_ = __syncthreads_count((long long)Sv >= k1);
      int seg = cnt_ - 1;
      if (tid == seg) {
        long long cum = (seg + 1 < 1024) ? (long long)S[seg + 1] : 0;
        int bin = seg * 2;
        if (cum + h1v >= k1) bin = seg * 2 + 1;
        else cum += h1v;
        spf21 = (t << 11) | bin;
        sk2 = (int)(k1 - cum);
      }
    }
    __syncthreads();
    int pf21 = spf21;

    // ---- part 5b: pass B hist (bits[9:0], 1024 bins) ----
    hs[tid] = 0;
    __syncthreads();
    for (int i = tid; i < nn; i += 1024) {
      unsigned bb = __float_as_uint(crow[i]);
      if ((int)(bb >> 10) == pf21) atomicAdd(&hs[bb & 1023], 1u);
    }
    __syncthreads();
    {
      unsigned Sv = bsufscan(hs[tid], S, wt, tid);
      long long kk = (long long)sk2;
      int cnt_ = __syncthreads_count((long long)Sv >= kk);
      int seg = cnt_ - 1;
      if (tid == seg) {
        long long cum = (seg + 1 < 1024) ? (long long)S[seg + 1] : 0;
        unsigned tb = ((unsigned)pf21 << 10) | (unsigned)seg;
        stb = tb;
        stie = (double)(kk - cum) * (double)__uint_as_float(tb);
      }
    }
    __syncthreads();

    // ---- part 5c: final sum over cbuf elems > tb ----
    unsigned tb = stb;
    double v = 0.0;
    for (int i = tid; i < nn; i += 1024) {
      unsigned bb = __float_as_uint(crow[i]);
      if (bb > tb) v += (double)__uint_as_float(bb);
    }
    v = dwave(v);
    if (lane == 0) rs[16 + wid] = v;
    __syncthreads();
    if (tid == 0) {
      double hi = 0, vt = 0;
      for (int i = 0; i < 16; ++i) { hi += rs[i]; vt += rs[16 + i]; }
      Fv = hi + vt + stie;
    }
  }

  // ---- part 6: fold into global accumulators; last block writes out ----
  if (tid == 0) {
    atomicAdd(&gacc[0], sA);
    atomicAdd(&gacc[1], sC);
    atomicAdd(&gacc[2], sD);
    atomicAdd(&gacc[3], Fv);
    atomicAdd(gnp, snpos);
    __threadfence();
    unsigned old = atomicAdd(done, 1u);
    if (old == (unsigned)B - 1) {
      __threadfence();
      double A = atomicAdd(&gacc[0], 0.0);
      double C = atomicAdd(&gacc[1], 0.0);
      double D = atomicAdd(&gacc[2], 0.0);
      double F = atomicAdd(&gacc[3], 0.0);
      int N = atomicAdd(gnp, 0);
      double Nd = N < 1 ? 1.0 : (double)N;
      out[0] = (float)(A / Nd);
      out[1] = (float)((D + F) / Nd);
      out[2] = (float)(C / Nd);
    }
  }
}

extern "C" void kernel_launch(void* const* d_in, const int* in_sizes, int n_in,
                              void* d_out, int out_size, void* d_ws,
                              size_t ws_size, hipStream_t stream) {
  const float* loc = (const float*)d_in[0];
  const float* conf = (const float*)d_in[1];
  const float* lm = (const float*)d_in[2];
  const float* priors = (const float*)d_in[3];
  const float* targets = (const float*)d_in[4];

  int P = in_sizes[3] / 4;
  int B = in_sizes[0] / (4 * P);
  int G = in_sizes[4] / (15 * B);
  int PTI = (P + 256 * PPI - 1) / (256 * PPI);
  int NIOU = B * PTI;
  int NGC = (G + GC - 1) / GC;
  int PC = 8;
  int NBP = B * NGC * PC;

  char* w = (char*)d_ws;
  size_t off = 0;
  // ---- zeroed region: bp + ghist + gacc + gnp + done ----
  unsigned long long* bp = (unsigned long long*)(w + off);
  off += (size_t)B * G * 8;
  unsigned* ghist = (unsigned*)(w + off);
  off += (size_t)B * 1024 * 4;
  double* gacc = (double*)(w + off);  // 8-aligned (prior offsets are)
  off += 4 * 8;
  int* gnp = (int*)(w + off);
  off += 4;
  unsigned* done = (unsigned*)(w + off);
  off += 4;
  size_t clear_bytes = off;
  // ---- non-zeroed (written unconditionally every call) ----
  off = (off + 255) & ~(size_t)255;
  float* bto = (float*)(w + off);  // reused as cbuf inside k_tail2
  off += (size_t)B * P * 4;
  int* bti = (int*)(w + off);
  off += (size_t)B * P * 4;
  float* mine = (float*)(w + off);
  off += (size_t)B * P * 4;
  double* pll = (double*)(w + off);
  off += (size_t)NIOU * 8;
  double* pllm = (double*)(w + off);
  off += (size_t)NIOU * 8;
  double* plc = (double*)(w + off);
  off += (size_t)NIOU * 8;
  double* msum = (double*)(w + off);
  off += (size_t)NIOU * 8;
  int* pnp = (int*)(w + off);
  off += (size_t)NIOU * 4;

  hipMemsetAsync(d_ws, 0, clear_bytes, stream);

  k_mm<<<NIOU + NBP, 256, 0, stream>>>(priors, targets, loc, conf, lm, bto,
                                       bti, bp, mine, ghist, pll, pllm, plc,
                                       msum, pnp, P, G, NIOU, PTI, NGC, PC);
  k_tail2<<<B, 1024, 0, stream>>>(bp, bto, bti, conf, loc, lm, priors,
                                  targets, mine, ghist, pnp, msum, pll, pllm,
                                  plc, gacc, gnp, done, (float*)d_out, P, G,
                                  PTI, B);
}